// Round 2
// baseline (1557.029 us; speedup 1.0000x reference)
//
#include <hip/hip_runtime.h>

#define N_NODES 100000
#define N_EDGES 1600000
#define N_GRAPHS 64
#define NBUCK 782        // ceil(N_NODES / 128)
#define BCAP 4096        // bucket capacity (mean occupancy 2048)

// ---------------- CSR build ----------------

__global__ __launch_bounds__(256) void k_zero_int(int* __restrict__ p, int n) {
  int i = blockIdx.x * 256 + threadIdx.x;
  if (i < n) p[i] = 0;
}

// fused: degree histogram + dst-bucket scatter of (src,dst) pairs
__global__ __launch_bounds__(256) void k_hist_bucket(const int* __restrict__ ei, int* __restrict__ deg,
                                                     int* __restrict__ bcnt, int2* __restrict__ bpair) {
  int e = blockIdx.x * 256 + threadIdx.x;
  if (e < N_EDGES) {
    int s = ei[e];
    int d = ei[N_EDGES + e];
    atomicAdd(&deg[d], 1);
    int b = d >> 7;
    int pos = atomicAdd(&bcnt[b], 1);
    if (pos < BCAP) bpair[(size_t)b * BCAP + pos] = make_int2(s, d);
  }
}

// exclusive scan within 256-blocks, emit block sums
__global__ __launch_bounds__(256) void k_scan1(const int* __restrict__ deg, int* __restrict__ part,
                                               int* __restrict__ bsum) {
  __shared__ int tmp[256];
  int i = blockIdx.x * 256 + threadIdx.x;
  int v = (i < N_NODES) ? deg[i] : 0;
  tmp[threadIdx.x] = v;
  __syncthreads();
  for (int o = 1; o < 256; o <<= 1) {
    int t = (threadIdx.x >= o) ? tmp[threadIdx.x - o] : 0;
    __syncthreads();
    tmp[threadIdx.x] += t;
    __syncthreads();
  }
  if (i < N_NODES) part[i] = tmp[threadIdx.x] - v;  // exclusive
  if (threadIdx.x == 255) bsum[blockIdx.x] = tmp[255];
}

__global__ __launch_bounds__(512) void k_scan2(const int* __restrict__ bsum, int* __restrict__ boff, int nb) {
  __shared__ int tmp[512];
  int v = ((int)threadIdx.x < nb) ? bsum[threadIdx.x] : 0;
  tmp[threadIdx.x] = v;
  __syncthreads();
  for (int o = 1; o < 512; o <<= 1) {
    int t = (threadIdx.x >= o) ? tmp[threadIdx.x - o] : 0;
    __syncthreads();
    tmp[threadIdx.x] += t;
    __syncthreads();
  }
  if ((int)threadIdx.x < nb) boff[threadIdx.x] = tmp[threadIdx.x] - v;  // exclusive
}

__global__ __launch_bounds__(256) void k_scan3(const int* __restrict__ part, const int* __restrict__ boff,
                                               int* __restrict__ rowptr, int* __restrict__ cursor) {
  int i = blockIdx.x * 256 + threadIdx.x;
  if (i < N_NODES) {
    int r = part[i] + boff[i >> 8];
    rowptr[i] = r;
    cursor[i] = r;
  } else if (i == N_NODES) {
    rowptr[N_NODES] = N_EDGES;
  }
}

// per-bucket scatter: csr writes land in a contiguous ~8KB window per bucket
__global__ __launch_bounds__(256) void k_scatter(const int* __restrict__ bcnt, const int2* __restrict__ bpair,
                                                 int* __restrict__ cursor, int* __restrict__ csr) {
  int b = blockIdx.x;
  int n = bcnt[b];
  if (n > BCAP) n = BCAP;
  for (int i = threadIdx.x; i < n; i += 256) {
    int2 p = bpair[(size_t)b * BCAP + i];
    int pos = atomicAdd(&cursor[p.y], 1);
    csr[pos] = p.x;
  }
}

// ---------------- Layer 1 (IN_CH=4) ----------------

__global__ __launch_bounds__(256) void k_l1_agg(const float* __restrict__ x, const int* __restrict__ rowptr,
                                                const int* __restrict__ csr, float* __restrict__ agg4) {
  int t = blockIdx.x * 256 + threadIdx.x;
  if (t >= N_NODES * 4) return;
  int node = t >> 2, c = t & 3;
  int s = rowptr[node], e = rowptr[node + 1];
  float a = 0.f;
  for (int p = s; p < e; ++p) a += x[(size_t)csr[p] * 4 + c];
  agg4[t] = a;
}

__global__ __launch_bounds__(256) void k_l1_comb(const float* __restrict__ x, const float* __restrict__ agg4,
                                                 const float* __restrict__ w_rel, const float* __restrict__ b_rel,
                                                 const float* __restrict__ w_root, float* __restrict__ out) {
  int t = blockIdx.x * 256 + threadIdx.x;
  int node = t >> 7, c = t & 127;
  if (node >= N_NODES) return;
  float acc = b_rel[c];
#pragma unroll
  for (int k = 0; k < 4; ++k) acc += agg4[node * 4 + k] * w_rel[k * 128 + c];
#pragma unroll
  for (int k = 0; k < 4; ++k) acc += x[node * 4 + k] * w_root[k * 128 + c];
  out[(size_t)node * 128 + c] = fmaxf(acc, 0.f);
}

// ---------------- Layers 2-4: pure gather-sum ----------------
// one wave per dst node; lane covers 2 cols (float2 => 512B/row coalesced)
__global__ __launch_bounds__(256) void k_agg2(const float* __restrict__ h, const int* __restrict__ rowptr,
                                              const int* __restrict__ csr, float* __restrict__ aggout) {
  int wid = (blockIdx.x * 256 + threadIdx.x) >> 6;
  int lane = threadIdx.x & 63;
  if (wid >= N_NODES) return;
  int s = rowptr[wid], e = rowptr[wid + 1];
  float2 acc = make_float2(0.f, 0.f);
  int p = s;
  for (; p + 4 <= e; p += 4) {
    int s0 = csr[p], s1 = csr[p + 1], s2 = csr[p + 2], s3 = csr[p + 3];
    float2 v0 = *(const float2*)&h[(size_t)s0 * 128 + lane * 2];
    float2 v1 = *(const float2*)&h[(size_t)s1 * 128 + lane * 2];
    float2 v2 = *(const float2*)&h[(size_t)s2 * 128 + lane * 2];
    float2 v3 = *(const float2*)&h[(size_t)s3 * 128 + lane * 2];
    acc.x += v0.x + v1.x + v2.x + v3.x;
    acc.y += v0.y + v1.y + v2.y + v3.y;
  }
  for (; p < e; ++p) {
    int s0 = csr[p];
    float2 v = *(const float2*)&h[(size_t)s0 * 128 + lane * 2];
    acc.x += v.x;
    acc.y += v.y;
  }
  *(float2*)&aggout[(size_t)wid * 128 + lane * 2] = acc;
}

// ---------------- Layers 2-4: fused dual GEMM + bias + ReLU ----------------
// out = relu(agg @ w_rel + h @ w_root + bias), K=256 in 2 staged chunks.
// 128x128 tile, 8x8 acc/thread (rows strided by 16 -> conflict-free a-reads).
// In-place safe: each block only reads its own 128 rows of h/agg (during
// staging) and writes the same rows at the end.
__global__ __launch_bounds__(256) void k_gemm2(const float* __restrict__ agg, const float* __restrict__ h,
                                               const float* __restrict__ w_rel, const float* __restrict__ w_root,
                                               const float* __restrict__ bias, float* __restrict__ out) {
  __shared__ float As[128][132];   // padded: bank = 4*row (mod 32) spreads row-groups
  __shared__ float Bs[128][128];
  const int n0 = blockIdx.x * 128;
  const int tid = threadIdx.x;
  const int lane = tid & 63, w = tid >> 6;
  const int tr = (w >> 1) * 8 + (lane >> 3);  // 0..15
  const int tc = (w & 1) * 8 + (lane & 7);    // 0..15
  const int c0 = tc * 8;
  float acc[8][8] = {};

#pragma unroll
  for (int chunk = 0; chunk < 2; ++chunk) {
    const float* src = (chunk == 0) ? agg : h;
    const float* wgt = (chunk == 0) ? w_rel : w_root;
    for (int i = tid; i < 4096; i += 256) {  // As: 128 rows x 32 float4
      int r = i >> 5, kq = i & 31;
      int gr = n0 + r;
      if (gr >= N_NODES) gr = N_NODES - 1;
      *(float4*)&As[r][kq * 4] = *(const float4*)&src[(size_t)gr * 128 + kq * 4];
    }
    for (int i = tid; i < 4096; i += 256) {  // Bs: 128 rows x 32 float4
      int k = i >> 5, cq = i & 31;
      *(float4*)&Bs[k][cq * 4] = *(const float4*)&wgt[(size_t)k * 128 + cq * 4];
    }
    __syncthreads();
    for (int k4 = 0; k4 < 32; ++k4) {
      float4 a[8];
#pragma unroll
      for (int m = 0; m < 8; ++m) a[m] = *(float4*)&As[tr + m * 16][k4 * 4];
      float4 b[4][2];
#pragma unroll
      for (int kk = 0; kk < 4; ++kk) {
        b[kk][0] = *(float4*)&Bs[k4 * 4 + kk][c0];
        b[kk][1] = *(float4*)&Bs[k4 * 4 + kk][c0 + 4];
      }
#pragma unroll
      for (int m = 0; m < 8; ++m) {
        const float* ap = (const float*)&a[m];
#pragma unroll
        for (int kk = 0; kk < 4; ++kk) {
          float av = ap[kk];
          const float* bp = (const float*)&b[kk][0];
#pragma unroll
          for (int j = 0; j < 8; ++j) acc[m][j] += av * bp[j];
        }
      }
    }
    __syncthreads();
  }

  float4 bi0 = *(const float4*)&bias[c0];
  float4 bi1 = *(const float4*)&bias[c0 + 4];
#pragma unroll
  for (int m = 0; m < 8; ++m) {
    int row = n0 + tr + m * 16;
    if (row < N_NODES) {
      float4 o0, o1;
      o0.x = fmaxf(acc[m][0] + bi0.x, 0.f);
      o0.y = fmaxf(acc[m][1] + bi0.y, 0.f);
      o0.z = fmaxf(acc[m][2] + bi0.z, 0.f);
      o0.w = fmaxf(acc[m][3] + bi0.w, 0.f);
      o1.x = fmaxf(acc[m][4] + bi1.x, 0.f);
      o1.y = fmaxf(acc[m][5] + bi1.y, 0.f);
      o1.z = fmaxf(acc[m][6] + bi1.z, 0.f);
      o1.w = fmaxf(acc[m][7] + bi1.w, 0.f);
      *(float4*)&out[(size_t)row * 128 + c0] = o0;
      *(float4*)&out[(size_t)row * 128 + c0 + 4] = o1;
    }
  }
}

// ---------------- Pooling ----------------

__device__ __forceinline__ int lower_bound_batch(const int* __restrict__ batch, int key) {
  int lo = 0, hi = N_NODES;
  while (lo < hi) {
    int mid = (lo + hi) >> 1;
    if (batch[mid] < key) lo = mid + 1;
    else hi = mid;
  }
  return lo;
}

__global__ __launch_bounds__(256) void k_pool1(const float* __restrict__ h, const int* __restrict__ batch,
                                               float* __restrict__ psum, float* __restrict__ pmax) {
  int b = blockIdx.x;
  int g = b >> 2, q = b & 3;
  int start = lower_bound_batch(batch, g);
  int end = lower_bound_batch(batch, g + 1);
  int c = threadIdx.x & 127;
  int half = threadIdx.x >> 7;
  float sum = 0.f, mx = -3.0e38f;
  for (int n = start + q * 2 + half; n < end; n += 8) {
    float v = h[(size_t)n * 128 + c];
    sum += v;
    mx = fmaxf(mx, v);
  }
  __shared__ float ss[128], sm[128];
  if (half == 0) { ss[c] = sum; sm[c] = mx; }
  __syncthreads();
  if (half == 1) { ss[c] += sum; sm[c] = fmaxf(sm[c], mx); }
  __syncthreads();
  if (half == 0) {
    psum[(size_t)b * 128 + c] = ss[c];
    pmax[(size_t)b * 128 + c] = sm[c];
  }
}

__global__ __launch_bounds__(128) void k_pool2(const float* __restrict__ psum, const float* __restrict__ pmax,
                                               const int* __restrict__ batch, float* __restrict__ pooled) {
  int g = blockIdx.x;
  int c = threadIdx.x;
  int start = lower_bound_batch(batch, g), end = lower_bound_batch(batch, g + 1);
  int count = end - start;
  float s = 0.f, m = -3.0e38f;
#pragma unroll
  for (int q = 0; q < 4; ++q) {
    s += psum[(size_t)(g * 4 + q) * 128 + c];
    m = fmaxf(m, pmax[(size_t)(g * 4 + q) * 128 + c]);
  }
  pooled[(size_t)g * 256 + c] = (count > 0) ? m : 0.f;
  pooled[(size_t)g * 256 + 128 + c] = s / fmaxf((float)count, 1.f);
}

// ---------------- Final FC (fused metadata branch) ----------------

__global__ __launch_bounds__(128) void k_fc(const float* __restrict__ pooled, const float* __restrict__ metadata,
                                            const float* __restrict__ convm_w, const float* __restrict__ convm_b,
                                            const float* __restrict__ fc_w, const float* __restrict__ fc_b,
                                            const float* __restrict__ fc2_w, const float* __restrict__ fc2_b,
                                            float* __restrict__ out) {
  int g = blockIdx.x;
  int tid = threadIdx.x;
  __shared__ float xc[260];
  xc[tid] = pooled[(size_t)g * 256 + tid];
  xc[128 + tid] = pooled[(size_t)g * 256 + 128 + tid];
  if (tid < 4) xc[256 + tid] = fmaxf(metadata[g] * convm_w[tid] + convm_b[tid], 0.f);
  __syncthreads();
  float acc = fc_b[tid];
  for (int k = 0; k < 260; ++k) acc += xc[k] * fc_w[(size_t)k * 128 + tid];
  float partial = fmaxf(acc, 0.f) * fc2_w[tid];
#pragma unroll
  for (int off = 32; off > 0; off >>= 1) partial += __shfl_down(partial, off);
  __shared__ float wred[2];
  if ((tid & 63) == 0) wred[tid >> 6] = partial;
  __syncthreads();
  if (tid == 0) out[g] = wred[0] + wred[1] + fc2_b[0];
}

// ---------------- launch ----------------

extern "C" void kernel_launch(void* const* d_in, const int* in_sizes, int n_in,
                              void* d_out, int out_size, void* d_ws, size_t ws_size,
                              hipStream_t stream) {
  const float* x = (const float*)d_in[0];
  const float* metadata = (const float*)d_in[1];
  const int* ei = (const int*)d_in[2];
  const int* batch = (const int*)d_in[3];
  const float* w_rel[4] = {(const float*)d_in[4], (const float*)d_in[7], (const float*)d_in[10], (const float*)d_in[13]};
  const float* b_rel[4] = {(const float*)d_in[5], (const float*)d_in[8], (const float*)d_in[11], (const float*)d_in[14]};
  const float* w_root[4] = {(const float*)d_in[6], (const float*)d_in[9], (const float*)d_in[12], (const float*)d_in[15]};
  const float* convm_w = (const float*)d_in[16];
  const float* convm_b = (const float*)d_in[17];
  const float* fc_w = (const float*)d_in[18];
  const float* fc_b = (const float*)d_in[19];
  const float* fc2_w = (const float*)d_in[20];
  const float* fc2_b = (const float*)d_in[21];
  float* out = (float*)d_out;

  char* ws = (char*)d_ws;
  size_t off = 0;
  auto alloc = [&](size_t bytes) {
    off = (off + 255) & ~(size_t)255;
    void* p = ws + off;
    off += bytes;
    return p;
  };
  int* misc = (int*)alloc((size_t)(N_NODES + NBUCK) * 4);  // deg + bcnt
  int* deg = misc;
  int* bcnt = misc + N_NODES;
  int* rowptr = (int*)alloc((size_t)(N_NODES + 1) * 4);
  int* cursor = (int*)alloc((size_t)N_NODES * 4);
  int* bsum = (int*)alloc(512 * 4);
  int* boff = (int*)alloc(512 * 4);
  int* csr = (int*)alloc((size_t)N_EDGES * 4);
  int2* bpair = (int2*)alloc((size_t)NBUCK * BCAP * 8);
  float* agg4 = (float*)alloc((size_t)N_NODES * 4 * 4);
  float* bufA = (float*)alloc((size_t)N_NODES * 128 * 4);  // h (in-place updated)
  float* bufB = (float*)alloc((size_t)N_NODES * 128 * 4);  // agg scratch
  float* psum = (float*)alloc((size_t)256 * 128 * 4);
  float* pmax = (float*)alloc((size_t)256 * 128 * 4);
  float* pooled = (float*)alloc((size_t)64 * 256 * 4);

  const int nblk_edges = (N_EDGES + 255) / 256;

  // CSR build
  k_zero_int<<<(N_NODES + NBUCK + 255) / 256, 256, 0, stream>>>(misc, N_NODES + NBUCK);
  k_hist_bucket<<<nblk_edges, 256, 0, stream>>>(ei, deg, bcnt, bpair);
  k_scan1<<<(N_NODES + 255) / 256, 256, 0, stream>>>(deg, rowptr, bsum);
  k_scan2<<<1, 512, 0, stream>>>(bsum, boff, (N_NODES + 255) / 256);
  k_scan3<<<(N_NODES + 1 + 255) / 256, 256, 0, stream>>>(rowptr, boff, rowptr, cursor);
  k_scatter<<<NBUCK, 256, 0, stream>>>(bcnt, bpair, cursor, csr);

  // Layer 1
  k_l1_agg<<<(N_NODES * 4 + 255) / 256, 256, 0, stream>>>(x, rowptr, csr, agg4);
  k_l1_comb<<<(N_NODES * 128 + 255) / 256, 256, 0, stream>>>(x, agg4, w_rel[0], b_rel[0], w_root[0], bufA);

  // Layers 2-4: agg (bufA -> bufB), fused GEMM (bufB,bufA -> bufA in-place)
  for (int l = 1; l < 4; ++l) {
    k_agg2<<<(N_NODES + 3) / 4, 256, 0, stream>>>(bufA, rowptr, csr, bufB);
    k_gemm2<<<(N_NODES + 127) / 128, 256, 0, stream>>>(bufB, bufA, w_rel[l], w_root[l], b_rel[l], bufA);
  }

  // Pool + FC
  k_pool1<<<256, 256, 0, stream>>>(bufA, batch, psum, pmax);
  k_pool2<<<64, 128, 0, stream>>>(psum, pmax, batch, pooled);
  k_fc<<<64, 128, 0, stream>>>(pooled, metadata, convm_w, convm_b, fc_w, fc_b, fc2_w, fc2_b, out);
}

// Round 4
// 1030.420 us; speedup vs baseline: 1.5111x; 1.5111x over previous
//
#include <hip/hip_runtime.h>

#define N_NODES 100000
#define N_EDGES 1600000
#define N_GRAPHS 64

// ---------------- CSR build ----------------

__global__ __launch_bounds__(256) void k_zero_int(int* __restrict__ p, int n) {
  int i = blockIdx.x * 256 + threadIdx.x;
  if (i < n) p[i] = 0;
}

__global__ __launch_bounds__(256) void k_hist(const int* __restrict__ ei, int* __restrict__ deg) {
  int e = blockIdx.x * 256 + threadIdx.x;
  if (e < N_EDGES) atomicAdd(&deg[ei[N_EDGES + e]], 1);
}

// exclusive scan within 256-blocks, emit block sums
__global__ __launch_bounds__(256) void k_scan1(const int* __restrict__ deg, int* __restrict__ part,
                                               int* __restrict__ bsum) {
  __shared__ int tmp[256];
  int i = blockIdx.x * 256 + threadIdx.x;
  int v = (i < N_NODES) ? deg[i] : 0;
  tmp[threadIdx.x] = v;
  __syncthreads();
  for (int o = 1; o < 256; o <<= 1) {
    int t = (threadIdx.x >= o) ? tmp[threadIdx.x - o] : 0;
    __syncthreads();
    tmp[threadIdx.x] += t;
    __syncthreads();
  }
  if (i < N_NODES) part[i] = tmp[threadIdx.x] - v;  // exclusive
  if (threadIdx.x == 255) bsum[blockIdx.x] = tmp[255];
}

__global__ __launch_bounds__(512) void k_scan2(const int* __restrict__ bsum, int* __restrict__ boff, int nb) {
  __shared__ int tmp[512];
  int v = ((int)threadIdx.x < nb) ? bsum[threadIdx.x] : 0;
  tmp[threadIdx.x] = v;
  __syncthreads();
  for (int o = 1; o < 512; o <<= 1) {
    int t = (threadIdx.x >= o) ? tmp[threadIdx.x - o] : 0;
    __syncthreads();
    tmp[threadIdx.x] += t;
    __syncthreads();
  }
  if ((int)threadIdx.x < nb) boff[threadIdx.x] = tmp[threadIdx.x] - v;  // exclusive
}

__global__ __launch_bounds__(256) void k_scan3(const int* __restrict__ part, const int* __restrict__ boff,
                                               int* __restrict__ rowptr, int* __restrict__ cursor) {
  int i = blockIdx.x * 256 + threadIdx.x;
  if (i < N_NODES) {
    int r = part[i] + boff[i >> 8];
    rowptr[i] = r;
    cursor[i] = r;
  } else if (i == N_NODES) {
    rowptr[N_NODES] = N_EDGES;
  }
}

__global__ __launch_bounds__(256) void k_fill(const int* __restrict__ ei, int* __restrict__ cursor,
                                              int* __restrict__ csr) {
  int e = blockIdx.x * 256 + threadIdx.x;
  if (e < N_EDGES) {
    int d = ei[N_EDGES + e];
    int p = atomicAdd(&cursor[d], 1);
    csr[p] = ei[e];
  }
}

// ---------------- Layer 1 (IN_CH=4) ----------------

__global__ __launch_bounds__(256) void k_l1_agg(const float* __restrict__ x, const int* __restrict__ rowptr,
                                                const int* __restrict__ csr, float* __restrict__ agg4) {
  int t = blockIdx.x * 256 + threadIdx.x;
  if (t >= N_NODES * 4) return;
  int node = t >> 2, c = t & 3;
  int s = rowptr[node], e = rowptr[node + 1];
  float a = 0.f;
  for (int p = s; p < e; ++p) a += x[(size_t)csr[p] * 4 + c];
  agg4[t] = a;
}

__global__ __launch_bounds__(256) void k_l1_comb(const float* __restrict__ x, const float* __restrict__ agg4,
                                                 const float* __restrict__ w_rel, const float* __restrict__ b_rel,
                                                 const float* __restrict__ w_root, float* __restrict__ out) {
  int t = blockIdx.x * 256 + threadIdx.x;
  int node = t >> 7, c = t & 127;
  if (node >= N_NODES) return;
  float acc = b_rel[c];
#pragma unroll
  for (int k = 0; k < 4; ++k) acc += agg4[node * 4 + k] * w_rel[k * 128 + c];
#pragma unroll
  for (int k = 0; k < 4; ++k) acc += x[node * 4 + k] * w_root[k * 128 + c];
  out[(size_t)node * 128 + c] = fmaxf(acc, 0.f);
}

// ---------------- Layers 2-4: pure gather-sum ----------------
// one wave per dst node; lane covers 2 cols (float2 => 512B/row coalesced)
__global__ __launch_bounds__(256) void k_agg2(const float* __restrict__ h, const int* __restrict__ rowptr,
                                              const int* __restrict__ csr, float* __restrict__ aggout) {
  int wid = (blockIdx.x * 256 + threadIdx.x) >> 6;
  int lane = threadIdx.x & 63;
  if (wid >= N_NODES) return;
  int s = rowptr[wid], e = rowptr[wid + 1];
  float2 acc = make_float2(0.f, 0.f);
  int p = s;
  for (; p + 4 <= e; p += 4) {
    int s0 = csr[p], s1 = csr[p + 1], s2 = csr[p + 2], s3 = csr[p + 3];
    float2 v0 = *(const float2*)&h[(size_t)s0 * 128 + lane * 2];
    float2 v1 = *(const float2*)&h[(size_t)s1 * 128 + lane * 2];
    float2 v2 = *(const float2*)&h[(size_t)s2 * 128 + lane * 2];
    float2 v3 = *(const float2*)&h[(size_t)s3 * 128 + lane * 2];
    acc.x += v0.x + v1.x + v2.x + v3.x;
    acc.y += v0.y + v1.y + v2.y + v3.y;
  }
  for (; p < e; ++p) {
    int s0 = csr[p];
    float2 v = *(const float2*)&h[(size_t)s0 * 128 + lane * 2];
    acc.x += v.x;
    acc.y += v.y;
  }
  *(float2*)&aggout[(size_t)wid * 128 + lane * 2] = acc;
}

// ---------------- Layers 2-4: fused dual GEMM + bias + ReLU ----------------
// out = relu(agg @ w_rel + h @ w_root + bias), K=256 via 2 sources x 4 chunks.
// 128x128 block tile, 256 threads, 8x8 per thread, K-chunk 32.
// A staged TRANSPOSED (AsT[k][m]) so the per-k A-fragment is a float4 read.
// LDS = 2*32*132*4 = 33.8 KB -> ~4 blocks/CU (16 waves). Per wave-k:
// 4 x ds_read_b128 (~8 cy) vs 64 FMA (128 cy) -> VALU-bound.
__global__ __launch_bounds__(256) void k_gemm3(const float* __restrict__ agg, const float* __restrict__ h,
                                               const float* __restrict__ w_rel, const float* __restrict__ w_root,
                                               const float* __restrict__ bias, float* __restrict__ out) {
  __shared__ float AsT[32][132];
  __shared__ float Bs[32][132];
  const int n0 = blockIdx.x * 128;
  const int tid = threadIdx.x;
  const int tr = tid >> 4;  // 0..15 -> rows tr*8..tr*8+7
  const int tc = tid & 15;  // 0..15 -> cols 4tc..4tc+3, 64+4tc..64+4tc+3
  float acc[8][8] = {};

  for (int chunk = 0; chunk < 2; ++chunk) {
    const float* src = (chunk == 0) ? agg : h;
    const float* wgt = (chunk == 0) ? w_rel : w_root;
    for (int k0 = 0; k0 < 128; k0 += 32) {
      // stage A transposed: 128 rows x 32 k (1024 float4s, 4 per thread)
#pragma unroll
      for (int t = 0; t < 4; ++t) {
        int idx = tid + t * 256;
        int r = idx & 127, q = idx >> 7;  // q = 0..7
        int gr = n0 + r;
        if (gr >= N_NODES) gr = N_NODES - 1;
        float4 v = *(const float4*)&src[(size_t)gr * 128 + k0 + q * 4];
        AsT[q * 4 + 0][r] = v.x;
        AsT[q * 4 + 1][r] = v.y;
        AsT[q * 4 + 2][r] = v.z;
        AsT[q * 4 + 3][r] = v.w;
      }
      // stage B: 32 k x 128 c
#pragma unroll
      for (int t = 0; t < 4; ++t) {
        int idx = tid + t * 256;
        int k = idx >> 5, cq = idx & 31;
        *(float4*)&Bs[k][cq * 4] = *(const float4*)&wgt[(size_t)(k0 + k) * 128 + cq * 4];
      }
      __syncthreads();
#pragma unroll 8
      for (int k = 0; k < 32; ++k) {
        float4 a0 = *(float4*)&AsT[k][tr * 8];
        float4 a1 = *(float4*)&AsT[k][tr * 8 + 4];
        float4 b0 = *(float4*)&Bs[k][tc * 4];
        float4 b1 = *(float4*)&Bs[k][tc * 4 + 64];
        float av[8] = {a0.x, a0.y, a0.z, a0.w, a1.x, a1.y, a1.z, a1.w};
        float bv[8] = {b0.x, b0.y, b0.z, b0.w, b1.x, b1.y, b1.z, b1.w};
#pragma unroll
        for (int m = 0; m < 8; ++m)
#pragma unroll
          for (int j = 0; j < 8; ++j) acc[m][j] += av[m] * bv[j];
      }
      __syncthreads();
    }
  }

  float4 bi0 = *(const float4*)&bias[tc * 4];
  float4 bi1 = *(const float4*)&bias[tc * 4 + 64];
  const float bb0[4] = {bi0.x, bi0.y, bi0.z, bi0.w};
  const float bb1[4] = {bi1.x, bi1.y, bi1.z, bi1.w};
#pragma unroll
  for (int m = 0; m < 8; ++m) {
    int row = n0 + tr * 8 + m;
    if (row < N_NODES) {
      float4 o0, o1;
      o0.x = fmaxf(acc[m][0] + bb0[0], 0.f);
      o0.y = fmaxf(acc[m][1] + bb0[1], 0.f);
      o0.z = fmaxf(acc[m][2] + bb0[2], 0.f);
      o0.w = fmaxf(acc[m][3] + bb0[3], 0.f);
      o1.x = fmaxf(acc[m][4] + bb1[0], 0.f);
      o1.y = fmaxf(acc[m][5] + bb1[1], 0.f);
      o1.z = fmaxf(acc[m][6] + bb1[2], 0.f);
      o1.w = fmaxf(acc[m][7] + bb1[3], 0.f);
      *(float4*)&out[(size_t)row * 128 + tc * 4] = o0;
      *(float4*)&out[(size_t)row * 128 + tc * 4 + 64] = o1;
    }
  }
}

// ---------------- Pooling ----------------

__device__ __forceinline__ int lower_bound_batch(const int* __restrict__ batch, int key) {
  int lo = 0, hi = N_NODES;
  while (lo < hi) {
    int mid = (lo + hi) >> 1;
    if (batch[mid] < key) lo = mid + 1;
    else hi = mid;
  }
  return lo;
}

__global__ __launch_bounds__(256) void k_pool1(const float* __restrict__ h, const int* __restrict__ batch,
                                               float* __restrict__ psum, float* __restrict__ pmax) {
  int b = blockIdx.x;
  int g = b >> 2, q = b & 3;
  int start = lower_bound_batch(batch, g);
  int end = lower_bound_batch(batch, g + 1);
  int c = threadIdx.x & 127;
  int half = threadIdx.x >> 7;
  float sum = 0.f, mx = -3.0e38f;
  for (int n = start + q * 2 + half; n < end; n += 8) {
    float v = h[(size_t)n * 128 + c];
    sum += v;
    mx = fmaxf(mx, v);
  }
  __shared__ float ss[128], sm[128];
  if (half == 0) { ss[c] = sum; sm[c] = mx; }
  __syncthreads();
  if (half == 1) { ss[c] += sum; sm[c] = fmaxf(sm[c], mx); }
  __syncthreads();
  if (half == 0) {
    psum[(size_t)b * 128 + c] = ss[c];
    pmax[(size_t)b * 128 + c] = sm[c];
  }
}

__global__ __launch_bounds__(128) void k_pool2(const float* __restrict__ psum, const float* __restrict__ pmax,
                                               const int* __restrict__ batch, float* __restrict__ pooled) {
  int g = blockIdx.x;
  int c = threadIdx.x;
  int start = lower_bound_batch(batch, g), end = lower_bound_batch(batch, g + 1);
  int count = end - start;
  float s = 0.f, m = -3.0e38f;
#pragma unroll
  for (int q = 0; q < 4; ++q) {
    s += psum[(size_t)(g * 4 + q) * 128 + c];
    m = fmaxf(m, pmax[(size_t)(g * 4 + q) * 128 + c]);
  }
  pooled[(size_t)g * 256 + c] = (count > 0) ? m : 0.f;
  pooled[(size_t)g * 256 + 128 + c] = s / fmaxf((float)count, 1.f);
}

// ---------------- Final FC (fused metadata branch) ----------------

__global__ __launch_bounds__(128) void k_fc(const float* __restrict__ pooled, const float* __restrict__ metadata,
                                            const float* __restrict__ convm_w, const float* __restrict__ convm_b,
                                            const float* __restrict__ fc_w, const float* __restrict__ fc_b,
                                            const float* __restrict__ fc2_w, const float* __restrict__ fc2_b,
                                            float* __restrict__ out) {
  int g = blockIdx.x;
  int tid = threadIdx.x;
  __shared__ float xc[260];
  xc[tid] = pooled[(size_t)g * 256 + tid];
  xc[128 + tid] = pooled[(size_t)g * 256 + 128 + tid];
  if (tid < 4) xc[256 + tid] = fmaxf(metadata[g] * convm_w[tid] + convm_b[tid], 0.f);
  __syncthreads();
  float acc = fc_b[tid];
  for (int k = 0; k < 260; ++k) acc += xc[k] * fc_w[(size_t)k * 128 + tid];
  float partial = fmaxf(acc, 0.f) * fc2_w[tid];
#pragma unroll
  for (int off = 32; off > 0; off >>= 1) partial += __shfl_down(partial, off);
  __shared__ float wred[2];
  if ((tid & 63) == 0) wred[tid >> 6] = partial;
  __syncthreads();
  if (tid == 0) out[g] = wred[0] + wred[1] + fc2_b[0];
}

// ---------------- launch ----------------

extern "C" void kernel_launch(void* const* d_in, const int* in_sizes, int n_in,
                              void* d_out, int out_size, void* d_ws, size_t ws_size,
                              hipStream_t stream) {
  const float* x = (const float*)d_in[0];
  const float* metadata = (const float*)d_in[1];
  const int* ei = (const int*)d_in[2];
  const int* batch = (const int*)d_in[3];
  const float* w_rel[4] = {(const float*)d_in[4], (const float*)d_in[7], (const float*)d_in[10], (const float*)d_in[13]};
  const float* b_rel[4] = {(const float*)d_in[5], (const float*)d_in[8], (const float*)d_in[11], (const float*)d_in[14]};
  const float* w_root[4] = {(const float*)d_in[6], (const float*)d_in[9], (const float*)d_in[12], (const float*)d_in[15]};
  const float* convm_w = (const float*)d_in[16];
  const float* convm_b = (const float*)d_in[17];
  const float* fc_w = (const float*)d_in[18];
  const float* fc_b = (const float*)d_in[19];
  const float* fc2_w = (const float*)d_in[20];
  const float* fc2_b = (const float*)d_in[21];
  float* out = (float*)d_out;

  char* ws = (char*)d_ws;
  size_t off = 0;
  auto alloc = [&](size_t bytes) {
    off = (off + 255) & ~(size_t)255;
    void* p = ws + off;
    off += bytes;
    return p;
  };
  int* deg = (int*)alloc((size_t)N_NODES * 4);
  int* rowptr = (int*)alloc((size_t)(N_NODES + 1) * 4);
  int* cursor = (int*)alloc((size_t)N_NODES * 4);
  int* bsum = (int*)alloc(512 * 4);
  int* boff = (int*)alloc(512 * 4);
  int* csr = (int*)alloc((size_t)N_EDGES * 4);
  float* agg4 = (float*)alloc((size_t)N_NODES * 4 * 4);
  float* bufA = (float*)alloc((size_t)N_NODES * 128 * 4);  // h (in-place updated)
  float* bufB = (float*)alloc((size_t)N_NODES * 128 * 4);  // agg scratch
  float* psum = (float*)alloc((size_t)256 * 128 * 4);
  float* pmax = (float*)alloc((size_t)256 * 128 * 4);
  float* pooled = (float*)alloc((size_t)64 * 256 * 4);

  const int nblk_nodes = (N_NODES + 255) / 256;
  const int nblk_edges = (N_EDGES + 255) / 256;

  // CSR build (round-1 structure: hist + scan + atomic fill)
  k_zero_int<<<nblk_nodes, 256, 0, stream>>>(deg, N_NODES);
  k_hist<<<nblk_edges, 256, 0, stream>>>(ei, deg);
  k_scan1<<<nblk_nodes, 256, 0, stream>>>(deg, rowptr, bsum);
  k_scan2<<<1, 512, 0, stream>>>(bsum, boff, nblk_nodes);
  k_scan3<<<(N_NODES + 1 + 255) / 256, 256, 0, stream>>>(rowptr, boff, rowptr, cursor);
  k_fill<<<nblk_edges, 256, 0, stream>>>(ei, cursor, csr);

  // Layer 1
  k_l1_agg<<<(N_NODES * 4 + 255) / 256, 256, 0, stream>>>(x, rowptr, csr, agg4);
  k_l1_comb<<<(N_NODES * 128 + 255) / 256, 256, 0, stream>>>(x, agg4, w_rel[0], b_rel[0], w_root[0], bufA);

  // Layers 2-4: agg (bufA -> bufB), fused GEMM (bufB,bufA -> bufA in-place)
  for (int l = 1; l < 4; ++l) {
    k_agg2<<<(N_NODES + 3) / 4, 256, 0, stream>>>(bufA, rowptr, csr, bufB);
    k_gemm3<<<(N_NODES + 127) / 128, 256, 0, stream>>>(bufB, bufA, w_rel[l], w_root[l], b_rel[l], bufA);
  }

  // Pool + FC
  k_pool1<<<256, 256, 0, stream>>>(bufA, batch, psum, pmax);
  k_pool2<<<64, 128, 0, stream>>>(psum, pmax, batch, pooled);
  k_fc<<<64, 128, 0, stream>>>(pooled, metadata, convm_w, convm_b, fc_w, fc_b, fc2_w, fc2_b, out);
}